// Round 2
// baseline (277.426 us; speedup 1.0000x reference)
//
#include <hip/hip_runtime.h>

// diag(triggers * mask) for N=8192, fp32 out (256 MiB), poisoned each call.
// Single fused kernel: grid-stride 16B nontemporal zero-stream with an
// inline diagonal patch. Replaces hipMemsetAsync + diag kernel (2 dispatches,
// 251 us) with one store-bound dispatch.
//
// Diagonal logic: element index of chunk idx is b = 4*idx. Diagonal elements
// sit at i*(N+1) = i*8193. Let u = b % 8193. A 16B chunk [b, b+4) contains a
// diagonal element iff u == 0 (row b/8193, comp 0) or u >= 8190 (row
// b/8193 + 1, comp 8193-u). Only 8192 of 16.7M chunks hit -> branch is
// wave-uniform false almost everywhere; division by 8193 compiles to
// mul_hi magic (a few VALU ops, free in a store-bound kernel).

#define NN 8192u
constexpr unsigned DIAG   = NN + 1u;            // 8193
constexpr unsigned TOTAL4 = (NN * NN) / 4u;     // 16,777,216 16B stores

// Native clang vector type — accepted by __builtin_nontemporal_store,
// lowers to global_store_dwordx4 nt.
typedef float f32x4 __attribute__((ext_vector_type(4)));

__global__ __launch_bounds__(256) void fill_diag_kernel(
    const float* __restrict__ triggers,
    const int*   __restrict__ mask,
    f32x4*       __restrict__ out4)
{
    const unsigned stride = gridDim.x * blockDim.x;          // 524,288
    unsigned idx = blockIdx.x * blockDim.x + threadIdx.x;

    const f32x4 z = (f32x4){0.f, 0.f, 0.f, 0.f};

    // TOTAL4 / stride == 32 exactly -> no tail divergence.
    #pragma unroll 4
    for (; idx < TOTAL4; idx += stride) {
        unsigned b  = idx << 2;          // element index of component 0 (< 2^26)
        unsigned i0 = b / DIAG;          // magic-mul division by 8193
        unsigned u  = b - i0 * DIAG;     // b % 8193, in [0, 8192]

        if (u == 0u || u >= DIAG - 3u) {
            // This 16B chunk contains one diagonal element.
            unsigned row = (u == 0u) ? i0 : (i0 + 1u);
            unsigned off = (u == 0u) ? 0u : (DIAG - u);   // component 0..3
            float v = triggers[row] * (float)mask[row];
            f32x4 w = z;
            w[off & 3u] = v;
            __builtin_nontemporal_store(w, &out4[idx]);
        } else {
            __builtin_nontemporal_store(z, &out4[idx]);
        }
    }
}

extern "C" void kernel_launch(void* const* d_in, const int* in_sizes, int n_in,
                              void* d_out, int out_size, void* d_ws, size_t ws_size,
                              hipStream_t stream) {
    const float* triggers = (const float*)d_in[0];
    const int*   mask     = (const int*)d_in[1];
    f32x4*       out4     = (f32x4*)d_out;

    // 2048 blocks x 256 threads = 8 blocks/CU across 256 CUs, 32 chunks/thread.
    fill_diag_kernel<<<2048, 256, 0, stream>>>(triggers, mask, out4);
}

// Round 3
// 263.045 us; speedup vs baseline: 1.0547x; 1.0547x over previous
//
#include <hip/hip_runtime.h>

// diag(triggers * mask) for N=8192, fp32 out (256 MiB), poisoned each call.
// Single fused kernel: grid-stride 16B zero-stream (PLAIN stores — the
// nontemporal variant measured ~3.6 TB/s vs ~6.4 TB/s for plain dwordx4;
// nt bypasses L2 write combining on gfx950) with inline diagonal patch.
//
// Diagonal logic: element index of chunk idx is b = 4*idx. Diagonal elements
// sit at i*(N+1) = i*8193. Let u = b % 8193. A 16B chunk [b, b+4) contains a
// diagonal element iff u == 0 (row b/8193, comp 0) or u >= 8190 (row
// b/8193 + 1, comp 8193-u). Only 8192 of 16.7M chunks hit -> branch is
// almost always uniformly false; division by 8193 is a magic-mul.

#define NN 8192u
constexpr unsigned DIAG   = NN + 1u;            // 8193
constexpr unsigned TOTAL4 = (NN * NN) / 4u;     // 16,777,216 16B stores

typedef float f32x4 __attribute__((ext_vector_type(4)));

__global__ __launch_bounds__(256) void fill_diag_kernel(
    const float* __restrict__ triggers,
    const int*   __restrict__ mask,
    f32x4*       __restrict__ out4)
{
    const unsigned stride = gridDim.x * blockDim.x;          // 524,288
    unsigned idx = blockIdx.x * blockDim.x + threadIdx.x;

    // TOTAL4 / stride == 32 exactly -> no tail divergence.
    #pragma unroll 4
    for (; idx < TOTAL4; idx += stride) {
        unsigned b  = idx << 2;          // element index of component 0 (< 2^26)
        unsigned i0 = b / DIAG;          // magic-mul division by 8193
        unsigned u  = b - i0 * DIAG;     // b % 8193, in [0, 8192]

        f32x4 w = (f32x4){0.f, 0.f, 0.f, 0.f};
        if (__builtin_expect(u == 0u || u >= DIAG - 3u, 0)) {
            // This 16B chunk contains one diagonal element.
            unsigned row = (u == 0u) ? i0 : (i0 + 1u);
            unsigned off = (u == 0u) ? 0u : (DIAG - u);   // component 0..3
            w[off & 3u] = triggers[row] * (float)mask[row];
        }
        out4[idx] = w;   // plain global_store_dwordx4
    }
}

extern "C" void kernel_launch(void* const* d_in, const int* in_sizes, int n_in,
                              void* d_out, int out_size, void* d_ws, size_t ws_size,
                              hipStream_t stream) {
    const float* triggers = (const float*)d_in[0];
    const int*   mask     = (const int*)d_in[1];
    f32x4*       out4     = (f32x4*)d_out;

    // 2048 blocks x 256 threads = 8 blocks/CU across 256 CUs, 32 chunks/thread.
    fill_diag_kernel<<<2048, 256, 0, stream>>>(triggers, mask, out4);
}

// Round 4
// 254.225 us; speedup vs baseline: 1.0913x; 1.0347x over previous
//
#include <hip/hip_runtime.h>

// diag(triggers * mask) for N=8192, fp32 out (256 MiB), poisoned each call.
// Single fused dispatch, structured as an exact memset clone:
//   - each block owns a CONTIGUOUS 128 KiB region (8192 x 16B chunks),
//     zero-filled by a branch-free unrolled dwordx4 loop (one store site,
//     no per-store VALU beyond address increment — matches rocclr fill rate);
//   - __syncthreads() (drains vmcnt -> orders WAW within the block);
//   - threads 0..3 patch the <=4 diagonal elements in the block's window
//     with scalar stores. The divide-by-8193 runs once per block, not per
//     store (round-3 lesson: per-chunk div/branch cost ~2x on store BW).

#define NN 8192u
constexpr unsigned DIAG    = NN + 1u;              // 8193
constexpr unsigned CHUNKS  = (NN * NN) / 4u;       // 16,777,216 16B chunks
constexpr unsigned NBLK    = 2048u;                // 8 blocks/CU on 256 CUs
constexpr unsigned CPB     = CHUNKS / NBLK;        // 8192 chunks per block
constexpr unsigned EPB     = CPB * 4u;             // 32768 elements per block
constexpr unsigned ITER    = CPB / 256u;           // 32 stores per thread

typedef float f32x4 __attribute__((ext_vector_type(4)));

__global__ __launch_bounds__(256) void fill_diag_kernel(
    const float* __restrict__ triggers,
    const int*   __restrict__ mask,
    float*       __restrict__ out)
{
    f32x4* __restrict__ out4 = (f32x4*)out;
    const unsigned t    = threadIdx.x;
    const unsigned base = blockIdx.x * CPB + t;    // contiguous block region

    const f32x4 z = (f32x4){0.f, 0.f, 0.f, 0.f};

    // Pure zero stream: 32 coalesced dwordx4 stores, no branches, one site.
    #pragma unroll
    for (unsigned k = 0; k < ITER; ++k)
        out4[base + k * 256u] = z;

    // Order the patch stores after the zero stores (same block region).
    __syncthreads();

    if (t < 4u) {
        const unsigned lo = blockIdx.x * EPB;           // block element window
        const unsigned hi = lo + EPB;                   // [lo, hi)
        const unsigned i0 = (lo + DIAG - 1u) / DIAG;    // first diag row >= lo
        const unsigned i  = i0 + t;                     // candidate rows
        if (i < NN) {
            const unsigned pos = i * DIAG;              // i*(N+1), < 2^26
            if (pos < hi)                               // pos >= lo by ceil
                out[pos] = triggers[i] * (float)mask[i];
        }
    }
}

extern "C" void kernel_launch(void* const* d_in, const int* in_sizes, int n_in,
                              void* d_out, int out_size, void* d_ws, size_t ws_size,
                              hipStream_t stream) {
    const float* triggers = (const float*)d_in[0];
    const int*   mask     = (const int*)d_in[1];
    float*       out      = (float*)d_out;

    fill_diag_kernel<<<NBLK, 256, 0, stream>>>(triggers, mask, out);
}

// Round 5
// 251.634 us; speedup vs baseline: 1.1025x; 1.0103x over previous
//
#include <hip/hip_runtime.h>

// diag(triggers * mask) for N=8192.
// Output: 8192x8192 fp32, zero except out[i*(N+1)] = triggers[i]*mask[i].
// Harness poisons d_out each call -> must rewrite all 256 MiB every launch.
//
// Final structure (best measured across 5 variants, 251.2 us):
//   1) hipMemsetAsync — rocclr's tuned fill streams the 256 MiB of zeros at
//      ~6.5-6.6 TB/s (the write roofline). Every hand-rolled fused variant
//      measured equal or slower: nt-stores 3.6 TB/s (nt bypasses L2 write
//      combining), per-chunk div/branch ~5 TB/s, block-contiguous memset
//      clone ~6 TB/s.
//   2) tiny diag-writer kernel — 8192 scattered dword stores, ~3 us.
// Timed region is dominated by the harness's own 1 GiB poison fill
// (~163 us at 82% HBM peak) + ~44 us fixed overhead; controllable part
// (~45 us) is at the memory roofline.

#define N 8192

__global__ __launch_bounds__(1024) void diag_write_kernel(
    const float* __restrict__ triggers,
    const int* __restrict__ mask,
    float* __restrict__ out) {
    int i = blockIdx.x * blockDim.x + threadIdx.x;
    if (i < N) {
        size_t idx = (size_t)i * (size_t)(N + 1);  // row i, col i
        out[idx] = triggers[i] * (float)mask[i];
    }
}

extern "C" void kernel_launch(void* const* d_in, const int* in_sizes, int n_in,
                              void* d_out, int out_size, void* d_ws, size_t ws_size,
                              hipStream_t stream) {
    const float* triggers = (const float*)d_in[0];
    const int*   mask     = (const int*)d_in[1];
    float*       out      = (float*)d_out;

    // Zero the whole 256 MiB output (poisoned to 0xAA before each call).
    hipMemsetAsync(out, 0, (size_t)N * (size_t)N * sizeof(float), stream);

    // Write the 8192 diagonal elements (8 blocks x 1024 threads).
    diag_write_kernel<<<N / 1024, 1024, 0, stream>>>(triggers, mask, out);
}